// Round 2
// baseline (335.356 us; speedup 1.0000x reference)
//
#include <hip/hip_runtime.h>
#include <hip/hip_bf16.h>

// Problem constants (from reference setup_inputs)
#define N_NODES 10000
#define N_EDGES 320000
#define DIM_D   128
#define DIM_H   256

// Output layout (flat f32 concat, element offsets):
//   z  : [0,           2,560,000)
//   z1 : [2,560,000,   5,120,000)
//   z2 : [5,120,000,   7,680,000)
//   rw1: [7,680,000,   107,680,000)
//   rw2: [107,680,000, 207,680,000)
#define Z_ELEMS   (N_NODES * DIM_H)           // 2,560,000
#define RW_ELEMS  ((size_t)N_NODES * N_NODES) // 100,000,000
#define OFF_Z1    ((size_t)Z_ELEMS)
#define OFF_Z2    ((size_t)2 * Z_ELEMS)
#define OFF_RW1   ((size_t)3 * Z_ELEMS)
#define OFF_RW2   (OFF_RW1 + RW_ELEMS)

// --- vectorized zero fill: float4 grid-stride --------------------------------
// Zeroes 2*RW_ELEMS floats starting at p (16B-aligned: OFF_RW1*4 = 30,720,000
// bytes, divisible by 16). 50M float4 stores total.
__global__ void zero_fill_kernel(float4* __restrict__ p, size_t n4) {
    size_t i = (size_t)blockIdx.x * blockDim.x + threadIdx.x;
    size_t stride = (size_t)gridDim.x * blockDim.x;
    float4 z = make_float4(0.f, 0.f, 0.f, 0.f);
    for (; i < n4; i += stride) p[i] = z;
}

// --- rowsum[j] = sum of edge weights with source j ---------------------------
__global__ void rowsum_kernel(const int* __restrict__ ei,
                              const float* __restrict__ ew,
                              float* __restrict__ rowsum, int E) {
    int e = blockIdx.x * blockDim.x + threadIdx.x;
    if (e >= E) return;
    atomicAdd(&rowsum[ei[e]], ew[e]);   // ei[e] = edge_index[0][e] (source)
}

// --- scatter normalized edges into both rw1 and rw2 --------------------------
// rw[s,d] += w / (rowsum[d] + 1e-20)   (divisor indexed by COLUMN d, per the
// reference's broadcast of adj.sum(axis=1) over the last axis)
__global__ void scatter_kernel(const int* __restrict__ ei,
                               const float* __restrict__ ew,
                               const float* __restrict__ rowsum,
                               float* __restrict__ rw1,
                               float* __restrict__ rw2, int E, int N) {
    int e = blockIdx.x * blockDim.x + threadIdx.x;
    if (e >= E) return;
    int s = ei[e];
    int d = ei[E + e];
    float v = ew[e] / (rowsum[d] + 1e-20f);
    size_t off = (size_t)s * N + d;
    atomicAdd(&rw1[off], v);
    atomicAdd(&rw2[off], v);
}

// --- z = x @ W_enc, written to z, z1, z2 ------------------------------------
__global__ void gemm_kernel(const float* __restrict__ x,
                            const float* __restrict__ W,
                            float* __restrict__ out) {
    int idx = blockIdx.x * blockDim.x + threadIdx.x;   // N * H/4 threads
    int row = idx >> 6;            // H/4 = 64 col-groups per row
    int h4  = (idx & 63) << 2;
    if (row >= N_NODES) return;

    const float* xr = x + (size_t)row * DIM_D;
    float4 acc = make_float4(0.f, 0.f, 0.f, 0.f);
#pragma unroll 8
    for (int k = 0; k < DIM_D; ++k) {
        float xv = xr[k];
        float4 w = *reinterpret_cast<const float4*>(W + (size_t)k * DIM_H + h4);
        acc.x += xv * w.x;
        acc.y += xv * w.y;
        acc.z += xv * w.z;
        acc.w += xv * w.w;
    }
    size_t o = (size_t)row * DIM_H + h4;
    *reinterpret_cast<float4*>(out + o)          = acc;
    *reinterpret_cast<float4*>(out + OFF_Z1 + o) = acc;
    *reinterpret_cast<float4*>(out + OFF_Z2 + o) = acc;
}

extern "C" void kernel_launch(void* const* d_in, const int* in_sizes, int n_in,
                              void* d_out, int out_size, void* d_ws, size_t ws_size,
                              hipStream_t stream) {
    const float* x      = (const float*)d_in[0];
    const int*   ei     = (const int*)d_in[1];    // (2,E) row-major: [0..E)=src, [E..2E)=dst
    const float* ew     = (const float*)d_in[2];
    const float* W_enc  = (const float*)d_in[3];
    float* out = (float*)d_out;

    float* rowsum = (float*)d_ws;                 // N_NODES floats (40 KB)

    // 1) zero rowsum scratch (tiny, 40 KB)
    hipMemsetAsync(rowsum, 0, N_NODES * sizeof(float), stream);

    // 2) zero both rw regions (contiguous 800 MB) with our own float4 fill —
    //    the rocclr fillBufferAligned ran at only 1.6 TB/s for this region.
    {
        size_t n4 = 2 * RW_ELEMS / 4;             // 50,000,000 float4s
        zero_fill_kernel<<<2048, 256, 0, stream>>>(
            reinterpret_cast<float4*>(out + OFF_RW1), n4);
    }

    // 3) rowsum[j] = sum of outgoing edge weights of node j
    rowsum_kernel<<<(N_EDGES + 255) / 256, 256, 0, stream>>>(ei, ew, rowsum, N_EDGES);

    // 4) scatter normalized weights into rw1 and rw2
    scatter_kernel<<<(N_EDGES + 255) / 256, 256, 0, stream>>>(
        ei, ew, rowsum, out + OFF_RW1, out + OFF_RW2, N_EDGES, N_NODES);

    // 5) z = x @ W_enc  -> z, z1, z2
    int gthreads = N_NODES * (DIM_H / 4);         // 640,000
    gemm_kernel<<<(gthreads + 255) / 256, 256, 0, stream>>>(x, W_enc, out);
}

// Round 3
// 283.621 us; speedup vs baseline: 1.1824x; 1.1824x over previous
//
#include <hip/hip_runtime.h>
#include <hip/hip_bf16.h>

// Problem constants (from reference setup_inputs)
#define N_NODES 10000
#define N_EDGES 320000
#define DIM_D   128
#define DIM_H   256

// Output layout (flat f32 concat, element offsets):
#define Z_ELEMS   (N_NODES * DIM_H)           // 2,560,000
#define RW_ELEMS  ((size_t)N_NODES * N_NODES) // 100,000,000
#define OFF_Z1    ((size_t)Z_ELEMS)
#define OFF_Z2    ((size_t)2 * Z_ELEMS)
#define OFF_RW1   ((size_t)3 * Z_ELEMS)
#define OFF_RW2   (OFF_RW1 + RW_ELEMS)

// Workspace layout (byte offsets into d_ws):
//   rowsum : float[10000]   @ 0
//   cnt    : int[10000]     @ 40960
//   cursor : int[10000]     @ 81920
//   rowptr : int[10001]     @ 122880
//   col    : int[320000]    @ 163840
//   val    : float[320000]  @ 1443840   (ends at 2,723,840 B < 3 MB)
#define WS_ROWSUM 0
#define WS_CNT    40960
#define WS_CURSOR 81920
#define WS_ROWPTR 122880
#define WS_COL    163840
#define WS_VAL    1443840

// --- pass 1: per-source rowsum + degree count --------------------------------
__global__ void count_kernel(const int* __restrict__ ei,
                             const float* __restrict__ ew,
                             float* __restrict__ rowsum,
                             int* __restrict__ cnt, int E) {
    int e = blockIdx.x * blockDim.x + threadIdx.x;
    if (e >= E) return;
    int s = ei[e];
    atomicAdd(&rowsum[s], ew[e]);
    atomicAdd(&cnt[s], 1);
}

// --- pass 2: exclusive prefix sum over cnt -> rowptr (single block) ----------
__global__ __launch_bounds__(1024) void scan_kernel(const int* __restrict__ cnt,
                                                    int* __restrict__ rowptr) {
    __shared__ int part[1024];
    int t = threadIdx.x;
    int base = t * 10;                 // 1024*10 = 10240 >= 10000
    int local[10];
    int s = 0;
    for (int i = 0; i < 10; ++i) {
        int c = (base + i < N_NODES) ? cnt[base + i] : 0;
        local[i] = s;
        s += c;
    }
    part[t] = s;
    __syncthreads();
    for (int off = 1; off < 1024; off <<= 1) {
        int v = part[t];
        int add = (t >= off) ? part[t - off] : 0;
        __syncthreads();
        part[t] = v + add;
        __syncthreads();
    }
    int pre = (t > 0) ? part[t - 1] : 0;
    for (int i = 0; i < 10; ++i) {
        int r = base + i;
        if (r < N_NODES) rowptr[r] = pre + local[i];
    }
    if (t == 1023) rowptr[N_NODES] = part[1023];
}

// --- pass 3: fill CSR col/val (normalized by COLUMN rowsum, per reference) ---
__global__ void csr_fill_kernel(const int* __restrict__ ei,
                                const float* __restrict__ ew,
                                const float* __restrict__ rowsum,
                                const int* __restrict__ rowptr,
                                int* __restrict__ cursor,
                                int* __restrict__ col,
                                float* __restrict__ val, int E) {
    int e = blockIdx.x * blockDim.x + threadIdx.x;
    if (e >= E) return;
    int s = ei[e];
    int d = ei[E + e];
    int p = rowptr[s] + atomicAdd(&cursor[s], 1);
    col[p] = d;
    val[p] = ew[e] / (rowsum[d] + 1e-20f);
}

// --- pass 4: write each rw row exactly once ----------------------------------
// One block per row: zero 40KB LDS row, LDS-atomicAdd the row's edges
// (coalesces duplicate edges), stream LDS -> rw1 and rw2 with float4 stores.
__global__ __launch_bounds__(256) void rw_rows_kernel(const int* __restrict__ rowptr,
                                                      const int* __restrict__ col,
                                                      const float* __restrict__ val,
                                                      float* __restrict__ rw1,
                                                      float* __restrict__ rw2) {
    __shared__ float row[N_NODES];     // 40,000 B
    float4* row4 = reinterpret_cast<float4*>(row);
    const float4 z = make_float4(0.f, 0.f, 0.f, 0.f);
    int r = blockIdx.x;

    for (int i = threadIdx.x; i < N_NODES / 4; i += 256) row4[i] = z;
    __syncthreads();

    int beg = rowptr[r], end = rowptr[r + 1];
    for (int e = beg + threadIdx.x; e < end; e += 256)
        atomicAdd(&row[col[e]], val[e]);
    __syncthreads();

    float4* o1 = reinterpret_cast<float4*>(rw1 + (size_t)r * N_NODES);
    float4* o2 = reinterpret_cast<float4*>(rw2 + (size_t)r * N_NODES);
    for (int i = threadIdx.x; i < N_NODES / 4; i += 256) {
        float4 v = row4[i];
        o1[i] = v;
        o2[i] = v;
    }
}

// --- z = x @ W_enc, written to z, z1, z2 ------------------------------------
__global__ void gemm_kernel(const float* __restrict__ x,
                            const float* __restrict__ W,
                            float* __restrict__ out) {
    int idx = blockIdx.x * blockDim.x + threadIdx.x;   // N * H/4 threads
    int row = idx >> 6;            // H/4 = 64 col-groups per row
    int h4  = (idx & 63) << 2;
    if (row >= N_NODES) return;

    const float* xr = x + (size_t)row * DIM_D;
    float4 acc = make_float4(0.f, 0.f, 0.f, 0.f);
#pragma unroll 8
    for (int k = 0; k < DIM_D; ++k) {
        float xv = xr[k];
        float4 w = *reinterpret_cast<const float4*>(W + (size_t)k * DIM_H + h4);
        acc.x += xv * w.x;
        acc.y += xv * w.y;
        acc.z += xv * w.z;
        acc.w += xv * w.w;
    }
    size_t o = (size_t)row * DIM_H + h4;
    *reinterpret_cast<float4*>(out + o)          = acc;
    *reinterpret_cast<float4*>(out + OFF_Z1 + o) = acc;
    *reinterpret_cast<float4*>(out + OFF_Z2 + o) = acc;
}

extern "C" void kernel_launch(void* const* d_in, const int* in_sizes, int n_in,
                              void* d_out, int out_size, void* d_ws, size_t ws_size,
                              hipStream_t stream) {
    const float* x      = (const float*)d_in[0];
    const int*   ei     = (const int*)d_in[1];    // (2,E): [0..E)=src, [E..2E)=dst
    const float* ew     = (const float*)d_in[2];
    const float* W_enc  = (const float*)d_in[3];
    float* out = (float*)d_out;

    char* ws = (char*)d_ws;
    float* rowsum = (float*)(ws + WS_ROWSUM);
    int*   cnt    = (int*)(ws + WS_CNT);
    int*   cursor = (int*)(ws + WS_CURSOR);
    int*   rowptr = (int*)(ws + WS_ROWPTR);
    int*   col    = (int*)(ws + WS_COL);
    float* val    = (float*)(ws + WS_VAL);

    // zero rowsum + cnt + cursor in one small memset (120 KB)
    hipMemsetAsync(ws, 0, WS_ROWPTR, stream);

    // CSR build
    count_kernel<<<(N_EDGES + 255) / 256, 256, 0, stream>>>(ei, ew, rowsum, cnt, N_EDGES);
    scan_kernel<<<1, 1024, 0, stream>>>(cnt, rowptr);
    csr_fill_kernel<<<(N_EDGES + 255) / 256, 256, 0, stream>>>(
        ei, ew, rowsum, rowptr, cursor, col, val, N_EDGES);

    // single-pass rw1 + rw2 write (800 MB streaming, no global atomics)
    rw_rows_kernel<<<N_NODES, 256, 0, stream>>>(
        rowptr, col, val, out + OFF_RW1, out + OFF_RW2);

    // z = x @ W_enc -> z, z1, z2
    int gthreads = N_NODES * (DIM_H / 4);         // 640,000
    gemm_kernel<<<(gthreads + 255) / 256, 256, 0, stream>>>(x, W_enc, out);
}

// Round 4
// 241.521 us; speedup vs baseline: 1.3885x; 1.1743x over previous
//
#include <hip/hip_runtime.h>
#include <hip/hip_bf16.h>

// Problem constants (from reference setup_inputs)
#define N_NODES 10000
#define N_EDGES 320000
#define DIM_D   128
#define DIM_H   256

// Output layout (flat f32 concat, element offsets):
#define Z_ELEMS   (N_NODES * DIM_H)           // 2,560,000
#define RW_ELEMS  ((size_t)N_NODES * N_NODES) // 100,000,000
#define OFF_Z1    ((size_t)Z_ELEMS)
#define OFF_Z2    ((size_t)2 * Z_ELEMS)
#define OFF_RW1   ((size_t)3 * Z_ELEMS)
#define OFF_RW2   (OFF_RW1 + RW_ELEMS)

// Workspace layout (byte offsets into d_ws)
#define WS_ROWSUM 0
#define WS_CNT    40960
#define WS_CURSOR 81920
#define WS_ROWPTR 122880
#define WS_COL    163840
#define WS_VAL    1443840

// gemm tiling: BM=64 rows x BN=64 cols per block, K chunked by 32
#define GEMM_RB 157                 // ceil(10000/64)
#define GEMM_CB 4                   // 256/64
#define GEMM_TOTAL (GEMM_RB * GEMM_CB)  // 628

typedef float f32x4 __attribute__((ext_vector_type(4)));

__device__ inline void nt_store4(float* p, float4 v) {
    f32x4 t = {v.x, v.y, v.z, v.w};
    __builtin_nontemporal_store(t, (f32x4*)p);
}

// --- pass 1: per-source rowsum + degree count --------------------------------
__global__ void count_kernel(const int* __restrict__ ei,
                             const float* __restrict__ ew,
                             float* __restrict__ rowsum,
                             int* __restrict__ cnt, int E) {
    int e = blockIdx.x * blockDim.x + threadIdx.x;
    if (e >= E) return;
    int s = ei[e];
    atomicAdd(&rowsum[s], ew[e]);
    atomicAdd(&cnt[s], 1);
}

// --- pass 2: exclusive prefix sum over cnt -> rowptr (single block) ----------
__global__ __launch_bounds__(1024) void scan_kernel(const int* __restrict__ cnt,
                                                    int* __restrict__ rowptr) {
    __shared__ int part[1024];
    int t = threadIdx.x;
    int base = t * 10;                 // 1024*10 = 10240 >= 10000
    int local[10];
    int s = 0;
    for (int i = 0; i < 10; ++i) {
        int c = (base + i < N_NODES) ? cnt[base + i] : 0;
        local[i] = s;
        s += c;
    }
    part[t] = s;
    __syncthreads();
    for (int off = 1; off < 1024; off <<= 1) {
        int v = part[t];
        int add = (t >= off) ? part[t - off] : 0;
        __syncthreads();
        part[t] = v + add;
        __syncthreads();
    }
    int pre = (t > 0) ? part[t - 1] : 0;
    for (int i = 0; i < 10; ++i) {
        int r = base + i;
        if (r < N_NODES) rowptr[r] = pre + local[i];
    }
    if (t == 1023) rowptr[N_NODES] = part[1023];
}

// --- pass 3: fill CSR col/val (normalized by COLUMN rowsum, per reference) ---
__global__ void csr_fill_kernel(const int* __restrict__ ei,
                                const float* __restrict__ ew,
                                const float* __restrict__ rowsum,
                                const int* __restrict__ rowptr,
                                int* __restrict__ cursor,
                                int* __restrict__ col,
                                float* __restrict__ val, int E) {
    int e = blockIdx.x * blockDim.x + threadIdx.x;
    if (e >= E) return;
    int s = ei[e];
    int d = ei[E + e];
    int p = rowptr[s] + atomicAdd(&cursor[s], 1);
    col[p] = d;
    val[p] = ew[e] / (rowsum[d] + 1e-20f);
}

// --- pass 4 (fused): rw row writes + tiled gemm ------------------------------
// blocks [0, GEMM_TOTAL)           : z = x @ W_enc -> z, z1, z2 (LDS-tiled)
// blocks [GEMM_TOTAL, +N_NODES)    : one rw row each: zero 40KB LDS row,
//                                    LDS-atomicAdd edges, stream to rw1+rw2.
// Both paths share one 40,000 B static LDS buffer -> 4 blocks/CU.
__global__ __launch_bounds__(256) void fused_kernel(
        const int* __restrict__ rowptr,
        const int* __restrict__ col,
        const float* __restrict__ val,
        float* __restrict__ rw1,
        float* __restrict__ rw2,
        const float* __restrict__ x,
        const float* __restrict__ W,
        float* __restrict__ out) {
    __shared__ float smem[N_NODES];    // 40,000 B, unioned across both paths

    if (blockIdx.x >= GEMM_TOTAL) {
        // ---------------- rw row path ----------------
        int r = blockIdx.x - GEMM_TOTAL;
        float4* row4 = reinterpret_cast<float4*>(smem);
        const float4 z4 = make_float4(0.f, 0.f, 0.f, 0.f);

        for (int i = threadIdx.x; i < N_NODES / 4; i += 256) row4[i] = z4;
        __syncthreads();

        int beg = rowptr[r], end = rowptr[r + 1];
        for (int e = beg + threadIdx.x; e < end; e += 256)
            atomicAdd(&smem[col[e]], val[e]);
        __syncthreads();

        float* o1 = rw1 + (size_t)r * N_NODES;
        float* o2 = rw2 + (size_t)r * N_NODES;
        for (int i = threadIdx.x; i < N_NODES / 4; i += 256) {
            float4 v = row4[i];
            nt_store4(o1 + 4 * i, v);
            nt_store4(o2 + 4 * i, v);
        }
        return;
    }

    // ---------------- gemm path ----------------
    // xs: [64][33] floats (padded stride vs bank conflicts) = 2112 floats
    // ws: [32][64] floats                                    = 2048 floats
    float* xs = smem;
    float* wsm = smem + 64 * 33;

    int rb = blockIdx.x >> 2;          // row block 0..156
    int cb = blockIdx.x & 3;           // col block 0..3
    int r_base = rb * 64;
    int c_base = cb * 64;

    int t  = threadIdx.x;
    int tr = t >> 4;                   // 0..15
    int tc = t & 15;                   // 0..15

    float acc[4][4];
#pragma unroll
    for (int i = 0; i < 4; ++i)
#pragma unroll
        for (int j = 0; j < 4; ++j) acc[i][j] = 0.f;

    for (int k0 = 0; k0 < DIM_D; k0 += 32) {
        // load x tile: 64 rows x 32 k = 512 float4, 2 per thread
#pragma unroll
        for (int q = t; q < 512; q += 256) {
            int row = q >> 3;          // 0..63
            int c4  = q & 7;           // 0..7
            int grow = r_base + row;
            float4 f = (grow < N_NODES)
                ? *reinterpret_cast<const float4*>(x + (size_t)grow * DIM_D + k0 + c4 * 4)
                : make_float4(0.f, 0.f, 0.f, 0.f);
            float* dst = xs + row * 33 + c4 * 4;
            dst[0] = f.x; dst[1] = f.y; dst[2] = f.z; dst[3] = f.w;
        }
        // load W tile: 32 k x 64 cols = 512 float4, 2 per thread
#pragma unroll
        for (int q = t; q < 512; q += 256) {
            int kk = q >> 4;           // 0..31
            int c4 = q & 15;           // 0..15
            float4 f = *reinterpret_cast<const float4*>(
                W + (size_t)(k0 + kk) * DIM_H + c_base + c4 * 4);
            *reinterpret_cast<float4*>(wsm + kk * 64 + c4 * 4) = f;
        }
        __syncthreads();

        for (int kk = 0; kk < 32; ++kk) {
            float4 w4 = *reinterpret_cast<const float4*>(wsm + kk * 64 + tc * 4);
#pragma unroll
            for (int i = 0; i < 4; ++i) {
                float a = xs[(tr * 4 + i) * 33 + kk];
                acc[i][0] += a * w4.x;
                acc[i][1] += a * w4.y;
                acc[i][2] += a * w4.z;
                acc[i][3] += a * w4.w;
            }
        }
        __syncthreads();
    }

#pragma unroll
    for (int i = 0; i < 4; ++i) {
        int row = r_base + tr * 4 + i;
        if (row >= N_NODES) continue;
        float4 v = make_float4(acc[i][0], acc[i][1], acc[i][2], acc[i][3]);
        size_t o = (size_t)row * DIM_H + c_base + tc * 4;
        nt_store4(out + o, v);
        nt_store4(out + OFF_Z1 + o, v);
        nt_store4(out + OFF_Z2 + o, v);
    }
}

extern "C" void kernel_launch(void* const* d_in, const int* in_sizes, int n_in,
                              void* d_out, int out_size, void* d_ws, size_t ws_size,
                              hipStream_t stream) {
    const float* x      = (const float*)d_in[0];
    const int*   ei     = (const int*)d_in[1];    // (2,E): [0..E)=src, [E..2E)=dst
    const float* ew     = (const float*)d_in[2];
    const float* W_enc  = (const float*)d_in[3];
    float* out = (float*)d_out;

    char* ws = (char*)d_ws;
    float* rowsum = (float*)(ws + WS_ROWSUM);
    int*   cnt    = (int*)(ws + WS_CNT);
    int*   cursor = (int*)(ws + WS_CURSOR);
    int*   rowptr = (int*)(ws + WS_ROWPTR);
    int*   col    = (int*)(ws + WS_COL);
    float* val    = (float*)(ws + WS_VAL);

    // zero rowsum + cnt + cursor (120 KB)
    hipMemsetAsync(ws, 0, WS_ROWPTR, stream);

    // CSR build
    count_kernel<<<(N_EDGES + 255) / 256, 256, 0, stream>>>(ei, ew, rowsum, cnt, N_EDGES);
    scan_kernel<<<1, 1024, 0, stream>>>(cnt, rowptr);
    csr_fill_kernel<<<(N_EDGES + 255) / 256, 256, 0, stream>>>(
        ei, ew, rowsum, rowptr, cursor, col, val, N_EDGES);

    // fused: tiled gemm (628 blocks) + rw rows (10000 blocks)
    fused_kernel<<<GEMM_TOTAL + N_NODES, 256, 0, stream>>>(
        rowptr, col, val, out + OFF_RW1, out + OFF_RW2, x, W_enc, out);
}

// Round 5
// 234.926 us; speedup vs baseline: 1.4275x; 1.0281x over previous
//
#include <hip/hip_runtime.h>
#include <hip/hip_bf16.h>

// Problem constants (from reference setup_inputs)
#define N_NODES 10000
#define N_EDGES 320000
#define DIM_D   128
#define DIM_H   256

// Output layout (flat f32 concat, element offsets):
#define Z_ELEMS   (N_NODES * DIM_H)           // 2,560,000
#define RW_ELEMS  ((size_t)N_NODES * N_NODES) // 100,000,000
#define OFF_Z1    ((size_t)Z_ELEMS)
#define OFF_Z2    ((size_t)2 * Z_ELEMS)
#define OFF_RW1   ((size_t)3 * Z_ELEMS)
#define OFF_RW2   (OFF_RW1 + RW_ELEMS)

// Workspace layout (byte offsets into d_ws)
#define WS_ROWSUM 0
#define WS_CNT    40960
#define WS_CURSOR 81920
#define WS_ROWPTR 122880
#define WS_COL    163840
#define WS_VAL    1443840

// gemm tiling: BM=128 rows x BN=64 cols per block (512 threads), K chunked 32
#define GEMM_RB 79                  // ceil(10000/128)
#define GEMM_CB 4                   // 256/64
#define GEMM_TOTAL (GEMM_RB * GEMM_CB)  // 316

// --- pass 1: per-source rowsum + degree count --------------------------------
__global__ void count_kernel(const int* __restrict__ ei,
                             const float* __restrict__ ew,
                             float* __restrict__ rowsum,
                             int* __restrict__ cnt, int E) {
    int e = blockIdx.x * blockDim.x + threadIdx.x;
    if (e >= E) return;
    int s = ei[e];
    atomicAdd(&rowsum[s], ew[e]);
    atomicAdd(&cnt[s], 1);
}

// --- pass 2: exclusive prefix sum over cnt -> rowptr (single block) ----------
__global__ __launch_bounds__(1024) void scan_kernel(const int* __restrict__ cnt,
                                                    int* __restrict__ rowptr) {
    __shared__ int part[1024];
    int t = threadIdx.x;
    int base = t * 10;                 // 1024*10 = 10240 >= 10000
    int local[10];
    int s = 0;
    for (int i = 0; i < 10; ++i) {
        int c = (base + i < N_NODES) ? cnt[base + i] : 0;
        local[i] = s;
        s += c;
    }
    part[t] = s;
    __syncthreads();
    for (int off = 1; off < 1024; off <<= 1) {
        int v = part[t];
        int add = (t >= off) ? part[t - off] : 0;
        __syncthreads();
        part[t] = v + add;
        __syncthreads();
    }
    int pre = (t > 0) ? part[t - 1] : 0;
    for (int i = 0; i < 10; ++i) {
        int r = base + i;
        if (r < N_NODES) rowptr[r] = pre + local[i];
    }
    if (t == 1023) rowptr[N_NODES] = part[1023];
}

// --- pass 3: fill CSR col/val (normalized by COLUMN rowsum, per reference) ---
__global__ void csr_fill_kernel(const int* __restrict__ ei,
                                const float* __restrict__ ew,
                                const float* __restrict__ rowsum,
                                const int* __restrict__ rowptr,
                                int* __restrict__ cursor,
                                int* __restrict__ col,
                                float* __restrict__ val, int E) {
    int e = blockIdx.x * blockDim.x + threadIdx.x;
    if (e >= E) return;
    int s = ei[e];
    int d = ei[E + e];
    int p = rowptr[s] + atomicAdd(&cursor[s], 1);
    col[p] = d;
    val[p] = ew[e] / (rowsum[d] + 1e-20f);
}

// --- pass 4 (fused): rw row writes (one stream per block) + tiled gemm -------
// blocks [0, GEMM_TOTAL)                 : z = x @ W_enc -> z, z1, z2
// blocks [GEMM_TOTAL, +2*N_NODES)        : one 40KB rw row each. Blocks
//   [GEMM_TOTAL, +N_NODES) write rw1; the next N_NODES write rw2. Each
//   rebuilds the row from the L2-resident CSR, so every block emits a single
//   contiguous coalesced write stream (no dual-stream interleave).
// 512 threads, 40,000B LDS -> 4 blocks/CU x 8 waves = 32 waves/CU.
__global__ __launch_bounds__(512) void fused_kernel(
        const int* __restrict__ rowptr,
        const int* __restrict__ col,
        const float* __restrict__ val,
        float* __restrict__ rw1,
        float* __restrict__ rw2,
        const float* __restrict__ x,
        const float* __restrict__ W,
        float* __restrict__ out) {
    __shared__ float smem[N_NODES];    // 40,000 B, unioned across both paths

    if (blockIdx.x >= GEMM_TOTAL) {
        // ---------------- rw row path ----------------
        int b = blockIdx.x - GEMM_TOTAL;
        int r = (b >= N_NODES) ? b - N_NODES : b;
        float* dst_base = (b >= N_NODES) ? rw2 : rw1;

        float4* row4 = reinterpret_cast<float4*>(smem);
        const float4 z4 = make_float4(0.f, 0.f, 0.f, 0.f);

        for (int i = threadIdx.x; i < N_NODES / 4; i += 512) row4[i] = z4;
        __syncthreads();

        int beg = rowptr[r], end = rowptr[r + 1];
        for (int e = beg + threadIdx.x; e < end; e += 512)
            atomicAdd(&smem[col[e]], val[e]);
        __syncthreads();

        float4* o = reinterpret_cast<float4*>(dst_base + (size_t)r * N_NODES);
        for (int i = threadIdx.x; i < N_NODES / 4; i += 512)
            o[i] = row4[i];
        return;
    }

    // ---------------- gemm path ----------------
    // xs: [128][33] floats (padded) = 4224 floats (16,896 B)
    // ws: [32][64] floats           = 2048 floats  (8,192 B)
    float* xs = smem;
    float* wsm = smem + 128 * 33;

    int rb = blockIdx.x >> 2;          // row block 0..78
    int cb = blockIdx.x & 3;           // col block 0..3
    int r_base = rb * 128;
    int c_base = cb * 64;

    int t  = threadIdx.x;
    int tr = t >> 4;                   // 0..31  -> 4 rows each (128 rows)
    int tc = t & 15;                   // 0..15  -> 4 cols each (64 cols)

    float acc[4][4];
#pragma unroll
    for (int i = 0; i < 4; ++i)
#pragma unroll
        for (int j = 0; j < 4; ++j) acc[i][j] = 0.f;

    for (int k0 = 0; k0 < DIM_D; k0 += 32) {
        // x tile: 128 rows x 32 k = 1024 float4, 2 per thread
#pragma unroll
        for (int q = t; q < 1024; q += 512) {
            int row = q >> 3;          // 0..127
            int c4  = q & 7;           // 0..7
            int grow = r_base + row;
            float4 f = (grow < N_NODES)
                ? *reinterpret_cast<const float4*>(x + (size_t)grow * DIM_D + k0 + c4 * 4)
                : make_float4(0.f, 0.f, 0.f, 0.f);
            float* dst = xs + row * 33 + c4 * 4;
            dst[0] = f.x; dst[1] = f.y; dst[2] = f.z; dst[3] = f.w;
        }
        // W tile: 32 k x 64 cols = 512 float4, 1 per thread
        {
            int kk = t >> 4;           // 0..31
            int c4 = t & 15;           // 0..15
            float4 f = *reinterpret_cast<const float4*>(
                W + (size_t)(k0 + kk) * DIM_H + c_base + c4 * 4);
            *reinterpret_cast<float4*>(wsm + kk * 64 + c4 * 4) = f;
        }
        __syncthreads();

        for (int kk = 0; kk < 32; ++kk) {
            float4 w4 = *reinterpret_cast<const float4*>(wsm + kk * 64 + tc * 4);
#pragma unroll
            for (int i = 0; i < 4; ++i) {
                float a = xs[(tr * 4 + i) * 33 + kk];
                acc[i][0] += a * w4.x;
                acc[i][1] += a * w4.y;
                acc[i][2] += a * w4.z;
                acc[i][3] += a * w4.w;
            }
        }
        __syncthreads();
    }

#pragma unroll
    for (int i = 0; i < 4; ++i) {
        int row = r_base + tr * 4 + i;
        if (row >= N_NODES) continue;
        float4 v = make_float4(acc[i][0], acc[i][1], acc[i][2], acc[i][3]);
        size_t o = (size_t)row * DIM_H + c_base + tc * 4;
        *reinterpret_cast<float4*>(out + o)          = v;
        *reinterpret_cast<float4*>(out + OFF_Z1 + o) = v;
        *reinterpret_cast<float4*>(out + OFF_Z2 + o) = v;
    }
}

extern "C" void kernel_launch(void* const* d_in, const int* in_sizes, int n_in,
                              void* d_out, int out_size, void* d_ws, size_t ws_size,
                              hipStream_t stream) {
    const float* x      = (const float*)d_in[0];
    const int*   ei     = (const int*)d_in[1];    // (2,E): [0..E)=src, [E..2E)=dst
    const float* ew     = (const float*)d_in[2];
    const float* W_enc  = (const float*)d_in[3];
    float* out = (float*)d_out;

    char* ws = (char*)d_ws;
    float* rowsum = (float*)(ws + WS_ROWSUM);
    int*   cnt    = (int*)(ws + WS_CNT);
    int*   cursor = (int*)(ws + WS_CURSOR);
    int*   rowptr = (int*)(ws + WS_ROWPTR);
    int*   col    = (int*)(ws + WS_COL);
    float* val    = (float*)(ws + WS_VAL);

    // zero rowsum + cnt + cursor (120 KB)
    hipMemsetAsync(ws, 0, WS_ROWPTR, stream);

    // CSR build
    count_kernel<<<(N_EDGES + 255) / 256, 256, 0, stream>>>(ei, ew, rowsum, cnt, N_EDGES);
    scan_kernel<<<1, 1024, 0, stream>>>(cnt, rowptr);
    csr_fill_kernel<<<(N_EDGES + 255) / 256, 256, 0, stream>>>(
        ei, ew, rowsum, rowptr, cursor, col, val, N_EDGES);

    // fused: tiled gemm (316 blocks) + rw1 rows (10000) + rw2 rows (10000)
    fused_kernel<<<GEMM_TOTAL + 2 * N_NODES, 512, 0, stream>>>(
        rowptr, col, val, out + OFF_RW1, out + OFF_RW2, x, W_enc, out);
}